// Round 7
// baseline (1233.700 us; speedup 1.0000x reference)
//
#include <hip/hip_runtime.h>
#include <stdint.h>
#include <stddef.h>

// ---------------------------------------------------------------------------
// TwoHemiRNNTanh_asymmetric_single_readout  (B=512, T=400, hidden 258)
// R7 = R6 minus the misplaced pragma (hipcc default -ffp-contract=fast
// already contracts f16x2 mul+add to v_pk_fma_f16).
// v_pk_fma_f16 dot path (f16x2 vector math, f32 finalize per row) replaces
// the scalarized fdot2 fallback (~6 instr/pair -> ~1). zs folded into scan's
// chunk flush (sbuf already in LDS) -> zs kernel + 211MB re-read deleted.
// ---------------------------------------------------------------------------

typedef uint32_t u32x4 __attribute__((ext_vector_type(4)));
typedef __fp16   f16x2 __attribute__((ext_vector_type(2)));

#define F2(u) __builtin_bit_cast(f16x2, (uint32_t)(u))
#define ZH    __builtin_bit_cast(f16x2, (uint32_t)0)

#define TF_ROUND(x0, x1, r) { x0 += x1; x1 = ((x1) << (r)) | ((x1) >> (32 - (r))); x1 ^= x0; }

__host__ __device__ inline void tf2x32(uint32_t k0, uint32_t k1, uint32_t x0, uint32_t x1,
                                       uint32_t& o0, uint32_t& o1) {
  uint32_t ks2 = k0 ^ k1 ^ 0x1BD11BDAu;
  x0 += k0; x1 += k1;
  TF_ROUND(x0, x1, 13) TF_ROUND(x0, x1, 15) TF_ROUND(x0, x1, 26) TF_ROUND(x0, x1, 6)
  x0 += k1; x1 += ks2 + 1u;
  TF_ROUND(x0, x1, 17) TF_ROUND(x0, x1, 29) TF_ROUND(x0, x1, 16) TF_ROUND(x0, x1, 24)
  x0 += ks2; x1 += k0 + 2u;
  TF_ROUND(x0, x1, 13) TF_ROUND(x0, x1, 15) TF_ROUND(x0, x1, 26) TF_ROUND(x0, x1, 6)
  x0 += k0; x1 += k1 + 3u;
  TF_ROUND(x0, x1, 17) TF_ROUND(x0, x1, 29) TF_ROUND(x0, x1, 16) TF_ROUND(x0, x1, 24)
  x0 += k1; x1 += ks2 + 4u;
  TF_ROUND(x0, x1, 13) TF_ROUND(x0, x1, 15) TF_ROUND(x0, x1, 26) TF_ROUND(x0, x1, 6)
  x0 += ks2; x1 += k0 + 5u;
  o0 = x0; o1 = x1;
}

__device__ __forceinline__ float jax_erfinv(float x) {
  float w = -log1pf(-x * x);
  float p;
  if (w < 5.0f) {
    w -= 2.5f;
    p = 2.81022636e-08f;
    p = fmaf(p, w, 3.43273939e-07f);
    p = fmaf(p, w, -3.5233877e-06f);
    p = fmaf(p, w, -4.39150654e-06f);
    p = fmaf(p, w, 0.00021858087f);
    p = fmaf(p, w, -0.00125372503f);
    p = fmaf(p, w, -0.00417768164f);
    p = fmaf(p, w, 0.246640727f);
    p = fmaf(p, w, 1.50140941f);
  } else {
    w = sqrtf(w) - 3.0f;
    p = -0.000200214257f;
    p = fmaf(p, w, 0.000100950558f);
    p = fmaf(p, w, 0.00134934322f);
    p = fmaf(p, w, -0.00367342844f);
    p = fmaf(p, w, 0.00573950773f);
    p = fmaf(p, w, -0.0076224613f);
    p = fmaf(p, w, 0.00943887047f);
    p = fmaf(p, w, 1.00167406f);
    p = fmaf(p, w, 2.83297682f);
  }
  return p * x;
}

__device__ __forceinline__ float uni_from_bits(uint32_t bits) {
  float f = __uint_as_float((bits >> 9) | 0x3f800000u) - 1.0f;
  float x = f * 2.0f + (-0.99999994f);
  return fmaxf(-0.99999994f, x);
}

__device__ __forceinline__ float noise_from_bits(uint32_t bits) {
  float n = 1.41421356f * jax_erfinv(uni_from_bits(bits));
  return 0.15811388f * n;   // sqrt(2/A)*SIG = sqrt(10)*0.05
}

__device__ __forceinline__ float my_tanh(float x) {
  float e = __expf(2.0f * x);
  return 1.0f - 2.0f / (e + 1.0f);
}

__device__ __forceinline__ uint32_t packh2(float a, float b) {
  f16x2 h = __builtin_amdgcn_cvt_pkrtz(a, b);
  return __builtin_bit_cast(uint32_t, h);
}

// 8-lane allreduce: xor1,xor2 via DPP quad_perm (VALU); xor4 via ds_swizzle.
__device__ __forceinline__ float allred8(float x) {
  int t = __builtin_amdgcn_update_dpp(0, __float_as_int(x), 0xB1, 0xF, 0xF, true);
  x += __int_as_float(t);
  t = __builtin_amdgcn_update_dpp(0, __float_as_int(x), 0x4E, 0xF, 0xF, true);
  x += __int_as_float(t);
  t = __builtin_amdgcn_ds_swizzle(__float_as_int(x), 0x101F);
  x += __int_as_float(t);
  return x;
}

// packed-slot skew: kp in [0,128) -> 20*(kp>>4) + (kp&15); spans 160 dwords.
#define PK(kp) (20 * ((kp) >> 4) + ((kp) & 15))

// ---------------------------------------------------------------------------
__device__ __forceinline__ float wval(int j, int k,
    const float* w_ll, const float* w_rl, const float* w_lr, const float* w_rr) {
  if (j < 2) return (k < 2) ? w_ll[j * 2 + k] : w_rl[j * 256 + (k - 2)];
  return (k < 2) ? w_lr[(j - 2) * 2 + k] : w_rr[(j - 2) * 256 + (k - 2)];
}

// Wp: packed f16 pairs [258][128]; Wtail: f32 [258][2] (k=256,257).
__global__ __launch_bounds__(256) void build_w_kernel(
    const float* __restrict__ w_ll, const float* __restrict__ w_rl,
    const float* __restrict__ w_lr, const float* __restrict__ w_rr,
    uint32_t* __restrict__ Wp, float* __restrict__ Wtail) {
  int i = blockIdx.x * 256 + threadIdx.x;
  if (i < 258 * 128) {
    int j = i >> 7, kp = i & 127;
    float v0 = wval(j, 2 * kp, w_ll, w_rl, w_lr, w_rr);
    float v1 = wval(j, 2 * kp + 1, w_ll, w_rl, w_lr, w_rr);
    Wp[i] = packh2(v0, v1);
  }
  if (i < 516) {
    int j = i >> 1, k = 256 + (i & 1);
    Wtail[i] = wval(j, k, w_ll, w_rl, w_lr, w_rr);
  }
}

// ---------------------------------------------------------------------------
__global__ __launch_bounds__(256) void gen_uv_kernel(
    const float* __restrict__ xs, float* __restrict__ u, float* __restrict__ v,
    uint32_t k0a, uint32_t k0b, uint32_t k1a, uint32_t k1b) {
  uint32_t i = blockIdx.x * 256u + threadIdx.x;
  bool isv = i >= 409600u;
  uint32_t e = isv ? i - 409600u : i;
  uint32_t ka = isv ? k1a : k0a;
  uint32_t kb = isv ? k1b : k0b;
  uint32_t o0, o1;
  tf2x32(ka, kb, 0u, e, o0, o1);
  float val = xs[e] + noise_from_bits(o0 ^ o1);
  if (isv) v[e] = val; else u[e] = val;
}

// ---------------------------------------------------------------------------
__global__ __launch_bounds__(256) void gen_c_kernel(
    const float* __restrict__ u, const float* __restrict__ v,
    const float* __restrict__ w_xl, const float* __restrict__ w_xr,
    const float* __restrict__ b_ll, const float* __restrict__ b_rr,
    float* __restrict__ C, uint32_t ka, uint32_t kb) {
  uint32_t i = blockIdx.x * 256u + threadIdx.x;   // < 52,838,400
  uint32_t t = i / 132096u;
  uint32_t rem = i - t * 132096u;
  uint32_t b = rem / 258u;
  uint32_t j = rem - b * 258u;
  uint32_t o0, o1;
  tf2x32(ka, kb, 0u, i, o0, o1);
  float nz = noise_from_bits(o0 ^ o1);
  uint32_t bt = (b * 400u + t) * 2u;
  float inj;
  if (j < 2u) {
    float2 uu = *(const float2*)(u + bt);
    inj = w_xl[j * 2u] * uu.x + w_xl[j * 2u + 1u] * uu.y + b_ll[j];
  } else {
    uint32_t jr = j - 2u;
    float2 vv = *(const float2*)(v + bt);
    inj = w_xr[jr * 2u] * vv.x + w_xr[jr * 2u + 1u] * vv.y + b_rr[jr];
  }
  C[(size_t)(b * 400u + t) * 258u + j] = inj + nz;
}

// ---------------------------------------------------------------------------
// K_scan: 512 blocks x 512 thr, 1 batch row/block, 2 blocks/CU.
// Thread (g,ks): 4 rows (j0=2+4g) x 32 k, W as 16 packed u32x4 (64 VGPR).
// Dots via v_pk_fma_f16 (f16x2 acc), f32 finalize + allred8.
// zs computed per 8-step chunk from sbuf (LDS) -> no separate zs kernel.
// ---------------------------------------------------------------------------
__global__ __launch_bounds__(512, 4) void rnn_scan_kernel(
    const uint32_t* __restrict__ Wp, const float* __restrict__ Wtail,
    float* __restrict__ hsC, const float* __restrict__ w_ro,
    const float* __restrict__ b_ro) {
  __shared__ __align__(16) uint32_t hbp[2][168];
  __shared__ __align__(16) uint32_t wlp[2][168];
  __shared__ __align__(16) float cbuf[8][260];
  __shared__ __align__(16) float sbuf[8][260];
  __shared__ __align__(16) float wrol[260];

  const int tid = threadIdx.x;
  const int ks = tid & 7;
  const int g  = tid >> 3;
  const int j0 = 2 + 4 * g;

  // persistent packed W: 4 rows x 16 k-pairs
  u32x4 wv[4][4];
  float2 wt[4];
#pragma unroll
  for (int r = 0; r < 4; ++r) {
    const uint32_t* p = Wp + (j0 + r) * 128 + 16 * ks;
#pragma unroll
    for (int c = 0; c < 4; ++c) wv[r][c] = *(const u32x4*)(p + 4 * c);
    wt[r] = *(const float2*)(Wtail + (j0 + r) * 2);
  }
  const float bro = b_ro[0];

  // stage left-row weights (rows 0,1) packed into LDS, skewed layout
  if (tid < 256) {
    int row = tid >> 7, kp = tid & 127;
    wlp[row][PK(kp)] = Wp[row * 128 + kp];
  }
  if (tid < 4) {
    int row = tid >> 1;
    wlp[row][160 + (tid & 1)] = __float_as_uint(Wtail[row * 2 + (tid & 1)]);
  }
  if (tid < 258) {                       // w_ro remapped to jj order
    int jj = (tid < 2) ? (256 + tid) : (tid - 2);
    wrol[jj] = w_ro[tid];
  }
  for (int idx = tid; idx < 336; idx += 512) ((uint32_t*)hbp)[idx] = 0u;

  const float* gC = hsC + (size_t)blockIdx.x * 103200;
  float* gO       = hsC + (size_t)blockIdx.x * 103200;
  float* gZ       = hsC + (size_t)52838400 + (size_t)blockIdx.x * 400;

  // prologue: chunk 0 -> cbuf
  for (int idx = tid; idx < 2064; idx += 512) {
    int s = idx / 258, j = idx - 258 * s;
    int jj = (j < 2) ? (256 + j) : (j - 2);
    cbuf[s][jj] = gC[idx];
  }
  __syncthreads();

  float hcur[4] = {0.f, 0.f, 0.f, 0.f};
  float hL0 = 0.f, hL1 = 0.f;

#pragma unroll 1
  for (int cc = 0; cc < 50; ++cc) {
    float creg[5];
    const bool hn = (cc < 49);
    const int nb = (cc + 1) * 2064;
    if (hn) {
#pragma unroll
      for (int q = 0; q < 5; ++q) {
        int idx = tid + 512 * q;
        if (idx < 2064) creg[q] = gC[nb + idx];
      }
    }

#pragma unroll
    for (int s = 0; s < 8; ++s) {
      const int cur = s & 1, nxt = cur ^ 1;

      // main dot: 4 rows x 32 k as 64 pk_fma (f16x2 accumulators)
      f16x2 ah0 = ZH, ah1 = ZH, ah2 = ZH, ah3 = ZH;
#pragma unroll
      for (int c = 0; c < 4; ++c) {
        u32x4 hq = *(const u32x4*)&hbp[cur][20 * ks + 4 * c];
        u32x4 w0 = wv[0][c], w1 = wv[1][c], w2 = wv[2][c], w3 = wv[3][c];
        ah0 = F2(w0.x) * F2(hq.x) + ah0; ah0 = F2(w0.y) * F2(hq.y) + ah0;
        ah0 = F2(w0.z) * F2(hq.z) + ah0; ah0 = F2(w0.w) * F2(hq.w) + ah0;
        ah1 = F2(w1.x) * F2(hq.x) + ah1; ah1 = F2(w1.y) * F2(hq.y) + ah1;
        ah1 = F2(w1.z) * F2(hq.z) + ah1; ah1 = F2(w1.w) * F2(hq.w) + ah1;
        ah2 = F2(w2.x) * F2(hq.x) + ah2; ah2 = F2(w2.y) * F2(hq.y) + ah2;
        ah2 = F2(w2.z) * F2(hq.z) + ah2; ah2 = F2(w2.w) * F2(hq.w) + ah2;
        ah3 = F2(w3.x) * F2(hq.x) + ah3; ah3 = F2(w3.y) * F2(hq.y) + ah3;
        ah3 = F2(w3.z) * F2(hq.z) + ah3; ah3 = F2(w3.w) * F2(hq.w) + ah3;
      }
      float a0 = (float)ah0.x + (float)ah0.y;
      float a1 = (float)ah1.x + (float)ah1.y;
      float a2 = (float)ah2.x + (float)ah2.y;
      float a3 = (float)ah3.x + (float)ah3.y;

      // left rows (j=0,1): lanes 0..7 (same h chunks, wlp from LDS)
      float l0 = 0.f, l1 = 0.f;
      if (tid < 8) {
        f16x2 lh0 = ZH, lh1 = ZH;
#pragma unroll
        for (int c = 0; c < 4; ++c) {
          u32x4 hq = *(const u32x4*)&hbp[cur][20 * tid + 4 * c];
          u32x4 w0 = *(const u32x4*)&wlp[0][20 * tid + 4 * c];
          u32x4 w1 = *(const u32x4*)&wlp[1][20 * tid + 4 * c];
          lh0 = F2(w0.x) * F2(hq.x) + lh0; lh0 = F2(w0.y) * F2(hq.y) + lh0;
          lh0 = F2(w0.z) * F2(hq.z) + lh0; lh0 = F2(w0.w) * F2(hq.w) + lh0;
          lh1 = F2(w1.x) * F2(hq.x) + lh1; lh1 = F2(w1.y) * F2(hq.y) + lh1;
          lh1 = F2(w1.z) * F2(hq.z) + lh1; lh1 = F2(w1.w) * F2(hq.w) + lh1;
        }
        l0 = allred8((float)lh0.x + (float)lh0.y);
        l1 = allred8((float)lh1.x + (float)lh1.y);
      }

      a0 = allred8(a0); a1 = allred8(a1); a2 = allred8(a2); a3 = allred8(a3);

      const float t0 = __uint_as_float(hbp[cur][160]);
      const float t1 = __uint_as_float(hbp[cur][161]);

      // update right rows: lane ks==0 owns 4 rows
      if (ks == 0) {
        float4 cv = *(const float4*)&cbuf[s][4 * g];
        float pre0 = a0 + wt[0].x * t0 + wt[0].y * t1 + cv.x;
        float pre1 = a1 + wt[1].x * t0 + wt[1].y * t1 + cv.y;
        float pre2 = a2 + wt[2].x * t0 + wt[2].y * t1 + cv.z;
        float pre3 = a3 + wt[3].x * t0 + wt[3].y * t1 + cv.w;
        hcur[0] = 0.8f * hcur[0] + 0.2f * my_tanh(pre0);
        hcur[1] = 0.8f * hcur[1] + 0.2f * my_tanh(pre1);
        hcur[2] = 0.8f * hcur[2] + 0.2f * my_tanh(pre2);
        hcur[3] = 0.8f * hcur[3] + 0.2f * my_tanh(pre3);
        uint32_t p01 = packh2(hcur[0], hcur[1]);
        uint32_t p23 = packh2(hcur[2], hcur[3]);
        if (g == 63) {               // rows 254,255 packed; 256,257 f32 tail
          hbp[nxt][PK(127)] = p01;
          hbp[nxt][160] = __float_as_uint(hcur[2]);
          hbp[nxt][161] = __float_as_uint(hcur[3]);
        } else {
          hbp[nxt][PK(1 + 2 * g)] = p01;
          hbp[nxt][PK(2 + 2 * g)] = p23;
        }
        *(float4*)&sbuf[s][4 * g] = make_float4(hcur[0], hcur[1], hcur[2], hcur[3]);
      }

      // left updater: lane 0 owns rows 0,1 (h[0],h[1] -> pair kp=0)
      if (tid == 0) {
        float wl0t0 = __uint_as_float(wlp[0][160]);
        float wl0t1 = __uint_as_float(wlp[0][161]);
        float wl1t0 = __uint_as_float(wlp[1][160]);
        float wl1t1 = __uint_as_float(wlp[1][161]);
        float pre0 = l0 + wl0t0 * t0 + wl0t1 * t1 + cbuf[s][256];
        float pre1 = l1 + wl1t0 * t0 + wl1t1 * t1 + cbuf[s][257];
        hL0 = 0.8f * hL0 + 0.2f * my_tanh(pre0);
        hL1 = 0.8f * hL1 + 0.2f * my_tanh(pre1);
        hbp[nxt][0] = packh2(hL0, hL1);   // PK(0) == 0
        sbuf[s][256] = hL0;
        sbuf[s][257] = hL1;
      }

      __syncthreads();
    }

    // flush sbuf -> hs (coalesced)
    const int fb = cc * 2064;
    for (int idx = tid; idx < 2064; idx += 512) {
      int s = idx / 258, j = idx - 258 * s;
      int jj = (j < 2) ? (256 + j) : (j - 2);
      gO[fb + idx] = sbuf[s][jj];
    }

    // zs for the chunk's 8 timesteps: wave w handles s=w
    {
      int w = tid >> 6, lane = tid & 63;
      float zacc = 0.f;
#pragma unroll
      for (int q = 0; q < 5; ++q) {
        int jj = lane + 64 * q;
        if (jj < 258) zacc = fmaf(sbuf[w][jj], wrol[jj], zacc);
      }
#pragma unroll
      for (int m = 32; m >= 1; m >>= 1) zacc += __shfl_xor(zacc, m);
      if (lane == 0) gZ[cc * 8 + w] = zacc + bro;
    }

    // commit prefetched C chunk -> cbuf
    if (hn) {
#pragma unroll
      for (int q = 0; q < 5; ++q) {
        int idx = tid + 512 * q;
        if (idx < 2064) {
          int s = idx / 258, j = idx - 258 * s;
          int jj = (j < 2) ? (256 + j) : (j - 2);
          cbuf[s][jj] = creg[q];
        }
      }
    }
    __syncthreads();
  }
}

// ---------------------------------------------------------------------------
extern "C" void kernel_launch(void* const* d_in, const int* in_sizes, int n_in,
                              void* d_out, int out_size, void* d_ws, size_t ws_size,
                              hipStream_t stream) {
  const float* xs   = (const float*)d_in[0];
  const float* w_ll = (const float*)d_in[1];
  const float* b_ll = (const float*)d_in[2];
  const float* w_rr = (const float*)d_in[3];
  const float* b_rr = (const float*)d_in[4];
  const float* w_lr = (const float*)d_in[5];
  const float* w_rl = (const float*)d_in[6];
  const float* w_xl = (const float*)d_in[7];
  const float* w_xr = (const float*)d_in[8];
  const float* w_ro = (const float*)d_in[9];
  const float* b_ro = (const float*)d_in[10];

  float* hs = (float*)d_out;                    // 512*400*258

  uint32_t* Wp  = (uint32_t*)d_ws;              // 258*128 = 33,024 u32
  float* Wtail  = (float*)(Wp + 33024);         // 516
  float* u      = Wtail + 516;                  // 409,600
  float* v      = u + 409600;                   // 409,600

  uint32_t nk[3][2];
  for (uint32_t i = 0; i < 3; ++i) {
    uint32_t o0, o1;
    tf2x32(0u, 42u, 0u, i, o0, o1);
    nk[i][0] = o0; nk[i][1] = o1;
  }

  build_w_kernel<<<129, 256, 0, stream>>>(w_ll, w_rl, w_lr, w_rr, Wp, Wtail);
  gen_uv_kernel<<<3200, 256, 0, stream>>>(xs, u, v, nk[0][0], nk[0][1], nk[1][0], nk[1][1]);
  gen_c_kernel<<<206400, 256, 0, stream>>>(u, v, w_xl, w_xr, b_ll, b_rr, hs, nk[2][0], nk[2][1]);
  rnn_scan_kernel<<<512, 512, 0, stream>>>(Wp, Wtail, hs, w_ro, b_ro);
}

// Round 8
// 1021.304 us; speedup vs baseline: 1.2080x; 1.2080x over previous
//
#include <hip/hip_runtime.h>
#include <stdint.h>
#include <stddef.h>

// ---------------------------------------------------------------------------
// TwoHemiRNNTanh_asymmetric_single_readout  (B=512, T=400, hidden 258)
// R8: (a) inline-asm v_pk_fma_f16 for the dot (R7 proved clang scalarizes
// __fp16 vector math via promote-to-float, ~6 instr/pair); (b) raw
// s_waitcnt lgkmcnt(0) + s_barrier in the step loop (no vmcnt(0) drain of
// the chunk prefetch loads / flush stores at every step barrier).
// ---------------------------------------------------------------------------

typedef uint32_t u32x4 __attribute__((ext_vector_type(4)));
typedef __fp16   f16x2 __attribute__((ext_vector_type(2)));

#define TF_ROUND(x0, x1, r) { x0 += x1; x1 = ((x1) << (r)) | ((x1) >> (32 - (r))); x1 ^= x0; }

__host__ __device__ inline void tf2x32(uint32_t k0, uint32_t k1, uint32_t x0, uint32_t x1,
                                       uint32_t& o0, uint32_t& o1) {
  uint32_t ks2 = k0 ^ k1 ^ 0x1BD11BDAu;
  x0 += k0; x1 += k1;
  TF_ROUND(x0, x1, 13) TF_ROUND(x0, x1, 15) TF_ROUND(x0, x1, 26) TF_ROUND(x0, x1, 6)
  x0 += k1; x1 += ks2 + 1u;
  TF_ROUND(x0, x1, 17) TF_ROUND(x0, x1, 29) TF_ROUND(x0, x1, 16) TF_ROUND(x0, x1, 24)
  x0 += ks2; x1 += k0 + 2u;
  TF_ROUND(x0, x1, 13) TF_ROUND(x0, x1, 15) TF_ROUND(x0, x1, 26) TF_ROUND(x0, x1, 6)
  x0 += k0; x1 += k1 + 3u;
  TF_ROUND(x0, x1, 17) TF_ROUND(x0, x1, 29) TF_ROUND(x0, x1, 16) TF_ROUND(x0, x1, 24)
  x0 += k1; x1 += ks2 + 4u;
  TF_ROUND(x0, x1, 13) TF_ROUND(x0, x1, 15) TF_ROUND(x0, x1, 26) TF_ROUND(x0, x1, 6)
  x0 += ks2; x1 += k0 + 5u;
  o0 = x0; o1 = x1;
}

__device__ __forceinline__ float jax_erfinv(float x) {
  float w = -log1pf(-x * x);
  float p;
  if (w < 5.0f) {
    w -= 2.5f;
    p = 2.81022636e-08f;
    p = fmaf(p, w, 3.43273939e-07f);
    p = fmaf(p, w, -3.5233877e-06f);
    p = fmaf(p, w, -4.39150654e-06f);
    p = fmaf(p, w, 0.00021858087f);
    p = fmaf(p, w, -0.00125372503f);
    p = fmaf(p, w, -0.00417768164f);
    p = fmaf(p, w, 0.246640727f);
    p = fmaf(p, w, 1.50140941f);
  } else {
    w = sqrtf(w) - 3.0f;
    p = -0.000200214257f;
    p = fmaf(p, w, 0.000100950558f);
    p = fmaf(p, w, 0.00134934322f);
    p = fmaf(p, w, -0.00367342844f);
    p = fmaf(p, w, 0.00573950773f);
    p = fmaf(p, w, -0.0076224613f);
    p = fmaf(p, w, 0.00943887047f);
    p = fmaf(p, w, 1.00167406f);
    p = fmaf(p, w, 2.83297682f);
  }
  return p * x;
}

__device__ __forceinline__ float uni_from_bits(uint32_t bits) {
  float f = __uint_as_float((bits >> 9) | 0x3f800000u) - 1.0f;
  float x = f * 2.0f + (-0.99999994f);
  return fmaxf(-0.99999994f, x);
}

__device__ __forceinline__ float noise_from_bits(uint32_t bits) {
  float n = 1.41421356f * jax_erfinv(uni_from_bits(bits));
  return 0.15811388f * n;   // sqrt(2/A)*SIG = sqrt(10)*0.05
}

__device__ __forceinline__ float my_tanh(float x) {
  float e = __expf(2.0f * x);
  return 1.0f - 2.0f / (e + 1.0f);
}

__device__ __forceinline__ uint32_t packh2(float a, float b) {
  f16x2 h = __builtin_amdgcn_cvt_pkrtz(a, b);
  return __builtin_bit_cast(uint32_t, h);
}

// THE fix: force v_pk_fma_f16 (2 f16 MACs / instr). acc/w/h are f16x2 in u32.
__device__ __forceinline__ void pkfma(uint32_t& acc, uint32_t w, uint32_t h) {
  asm("v_pk_fma_f16 %0, %1, %2, %0" : "+v"(acc) : "v"(w), "v"(h));
}

__device__ __forceinline__ float cvt2f(uint32_t a) {
  f16x2 v = __builtin_bit_cast(f16x2, a);
  return (float)v.x + (float)v.y;
}

// step barrier: LDS visibility only — do NOT drain vmcnt (prefetch loads and
// flush stores stay in flight across step barriers; register deps on creg get
// their own compiler-inserted vmcnt wait at the chunk-end commit).
__device__ __forceinline__ void step_barrier() {
  asm volatile("s_waitcnt lgkmcnt(0)" ::: "memory");
  __builtin_amdgcn_s_barrier();
}

// 8-lane allreduce: xor1,xor2 via DPP quad_perm (VALU); xor4 via ds_swizzle.
__device__ __forceinline__ float allred8(float x) {
  int t = __builtin_amdgcn_update_dpp(0, __float_as_int(x), 0xB1, 0xF, 0xF, true);
  x += __int_as_float(t);
  t = __builtin_amdgcn_update_dpp(0, __float_as_int(x), 0x4E, 0xF, 0xF, true);
  x += __int_as_float(t);
  t = __builtin_amdgcn_ds_swizzle(__float_as_int(x), 0x101F);
  x += __int_as_float(t);
  return x;
}

// packed-slot skew: kp in [0,128) -> 20*(kp>>4) + (kp&15); spans 160 dwords.
#define PK(kp) (20 * ((kp) >> 4) + ((kp) & 15))

// ---------------------------------------------------------------------------
__device__ __forceinline__ float wval(int j, int k,
    const float* w_ll, const float* w_rl, const float* w_lr, const float* w_rr) {
  if (j < 2) return (k < 2) ? w_ll[j * 2 + k] : w_rl[j * 256 + (k - 2)];
  return (k < 2) ? w_lr[(j - 2) * 2 + k] : w_rr[(j - 2) * 256 + (k - 2)];
}

// Wp: packed f16 pairs [258][128]; Wtail: f32 [258][2] (k=256,257).
__global__ __launch_bounds__(256) void build_w_kernel(
    const float* __restrict__ w_ll, const float* __restrict__ w_rl,
    const float* __restrict__ w_lr, const float* __restrict__ w_rr,
    uint32_t* __restrict__ Wp, float* __restrict__ Wtail) {
  int i = blockIdx.x * 256 + threadIdx.x;
  if (i < 258 * 128) {
    int j = i >> 7, kp = i & 127;
    float v0 = wval(j, 2 * kp, w_ll, w_rl, w_lr, w_rr);
    float v1 = wval(j, 2 * kp + 1, w_ll, w_rl, w_lr, w_rr);
    Wp[i] = packh2(v0, v1);
  }
  if (i < 516) {
    int j = i >> 1, k = 256 + (i & 1);
    Wtail[i] = wval(j, k, w_ll, w_rl, w_lr, w_rr);
  }
}

// ---------------------------------------------------------------------------
__global__ __launch_bounds__(256) void gen_uv_kernel(
    const float* __restrict__ xs, float* __restrict__ u, float* __restrict__ v,
    uint32_t k0a, uint32_t k0b, uint32_t k1a, uint32_t k1b) {
  uint32_t i = blockIdx.x * 256u + threadIdx.x;
  bool isv = i >= 409600u;
  uint32_t e = isv ? i - 409600u : i;
  uint32_t ka = isv ? k1a : k0a;
  uint32_t kb = isv ? k1b : k0b;
  uint32_t o0, o1;
  tf2x32(ka, kb, 0u, e, o0, o1);
  float val = xs[e] + noise_from_bits(o0 ^ o1);
  if (isv) v[e] = val; else u[e] = val;
}

// ---------------------------------------------------------------------------
__global__ __launch_bounds__(256) void gen_c_kernel(
    const float* __restrict__ u, const float* __restrict__ v,
    const float* __restrict__ w_xl, const float* __restrict__ w_xr,
    const float* __restrict__ b_ll, const float* __restrict__ b_rr,
    float* __restrict__ C, uint32_t ka, uint32_t kb) {
  uint32_t i = blockIdx.x * 256u + threadIdx.x;   // < 52,838,400
  uint32_t t = i / 132096u;
  uint32_t rem = i - t * 132096u;
  uint32_t b = rem / 258u;
  uint32_t j = rem - b * 258u;
  uint32_t o0, o1;
  tf2x32(ka, kb, 0u, i, o0, o1);
  float nz = noise_from_bits(o0 ^ o1);
  uint32_t bt = (b * 400u + t) * 2u;
  float inj;
  if (j < 2u) {
    float2 uu = *(const float2*)(u + bt);
    inj = w_xl[j * 2u] * uu.x + w_xl[j * 2u + 1u] * uu.y + b_ll[j];
  } else {
    uint32_t jr = j - 2u;
    float2 vv = *(const float2*)(v + bt);
    inj = w_xr[jr * 2u] * vv.x + w_xr[jr * 2u + 1u] * vv.y + b_rr[jr];
  }
  C[(size_t)(b * 400u + t) * 258u + j] = inj + nz;
}

// ---------------------------------------------------------------------------
// K_scan: 512 blocks x 512 thr, 1 batch row/block, 2 blocks/CU.
// Thread (g,ks): 4 rows (j0=2+4g) x 32 k, W as 16 packed u32x4 (64 VGPR).
// Dots via asm v_pk_fma_f16, f32 finalize + allred8.
// zs computed per 8-step chunk from sbuf (LDS) -> no separate zs kernel.
// ---------------------------------------------------------------------------
__global__ __launch_bounds__(512, 4) void rnn_scan_kernel(
    const uint32_t* __restrict__ Wp, const float* __restrict__ Wtail,
    float* __restrict__ hsC, const float* __restrict__ w_ro,
    const float* __restrict__ b_ro) {
  __shared__ __align__(16) uint32_t hbp[2][168];
  __shared__ __align__(16) uint32_t wlp[2][168];
  __shared__ __align__(16) float cbuf[8][260];
  __shared__ __align__(16) float sbuf[8][260];
  __shared__ __align__(16) float wrol[260];

  const int tid = threadIdx.x;
  const int ks = tid & 7;
  const int g  = tid >> 3;
  const int j0 = 2 + 4 * g;

  // persistent packed W: 4 rows x 16 k-pairs
  u32x4 wv[4][4];
  float2 wt[4];
#pragma unroll
  for (int r = 0; r < 4; ++r) {
    const uint32_t* p = Wp + (j0 + r) * 128 + 16 * ks;
#pragma unroll
    for (int c = 0; c < 4; ++c) wv[r][c] = *(const u32x4*)(p + 4 * c);
    wt[r] = *(const float2*)(Wtail + (j0 + r) * 2);
  }
  const float bro = b_ro[0];

  // stage left-row weights (rows 0,1) packed into LDS, skewed layout
  if (tid < 256) {
    int row = tid >> 7, kp = tid & 127;
    wlp[row][PK(kp)] = Wp[row * 128 + kp];
  }
  if (tid < 4) {
    int row = tid >> 1;
    wlp[row][160 + (tid & 1)] = __float_as_uint(Wtail[row * 2 + (tid & 1)]);
  }
  if (tid < 258) {                       // w_ro remapped to jj order
    int jj = (tid < 2) ? (256 + tid) : (tid - 2);
    wrol[jj] = w_ro[tid];
  }
  for (int idx = tid; idx < 336; idx += 512) ((uint32_t*)hbp)[idx] = 0u;

  const float* gC = hsC + (size_t)blockIdx.x * 103200;
  float* gO       = hsC + (size_t)blockIdx.x * 103200;
  float* gZ       = hsC + (size_t)52838400 + (size_t)blockIdx.x * 400;

  // prologue: chunk 0 -> cbuf
  for (int idx = tid; idx < 2064; idx += 512) {
    int s = idx / 258, j = idx - 258 * s;
    int jj = (j < 2) ? (256 + j) : (j - 2);
    cbuf[s][jj] = gC[idx];
  }
  __syncthreads();

  float hcur[4] = {0.f, 0.f, 0.f, 0.f};
  float hL0 = 0.f, hL1 = 0.f;

#pragma unroll 1
  for (int cc = 0; cc < 50; ++cc) {
    float creg[5];
    const bool hn = (cc < 49);
    const int nb = (cc + 1) * 2064;
    if (hn) {
#pragma unroll
      for (int q = 0; q < 5; ++q) {
        int idx = tid + 512 * q;
        if (idx < 2064) creg[q] = gC[nb + idx];
      }
    }

#pragma unroll
    for (int s = 0; s < 8; ++s) {
      const int cur = s & 1, nxt = cur ^ 1;

      // main dot: 4 rows x 32 k as 64 v_pk_fma_f16
      uint32_t ac0 = 0u, ac1 = 0u, ac2 = 0u, ac3 = 0u;
#pragma unroll
      for (int c = 0; c < 4; ++c) {
        u32x4 hq = *(const u32x4*)&hbp[cur][20 * ks + 4 * c];
        u32x4 w0 = wv[0][c], w1 = wv[1][c], w2 = wv[2][c], w3 = wv[3][c];
        pkfma(ac0, w0.x, hq.x); pkfma(ac0, w0.y, hq.y);
        pkfma(ac0, w0.z, hq.z); pkfma(ac0, w0.w, hq.w);
        pkfma(ac1, w1.x, hq.x); pkfma(ac1, w1.y, hq.y);
        pkfma(ac1, w1.z, hq.z); pkfma(ac1, w1.w, hq.w);
        pkfma(ac2, w2.x, hq.x); pkfma(ac2, w2.y, hq.y);
        pkfma(ac2, w2.z, hq.z); pkfma(ac2, w2.w, hq.w);
        pkfma(ac3, w3.x, hq.x); pkfma(ac3, w3.y, hq.y);
        pkfma(ac3, w3.z, hq.z); pkfma(ac3, w3.w, hq.w);
      }
      float a0 = cvt2f(ac0);
      float a1 = cvt2f(ac1);
      float a2 = cvt2f(ac2);
      float a3 = cvt2f(ac3);

      // left rows (j=0,1): lanes 0..7 (wave 0 only; other waves skip via execz)
      float l0 = 0.f, l1 = 0.f;
      if (tid < 8) {
        uint32_t lc0 = 0u, lc1 = 0u;
#pragma unroll
        for (int c = 0; c < 4; ++c) {
          u32x4 hq = *(const u32x4*)&hbp[cur][20 * tid + 4 * c];
          u32x4 w0 = *(const u32x4*)&wlp[0][20 * tid + 4 * c];
          u32x4 w1 = *(const u32x4*)&wlp[1][20 * tid + 4 * c];
          pkfma(lc0, w0.x, hq.x); pkfma(lc0, w0.y, hq.y);
          pkfma(lc0, w0.z, hq.z); pkfma(lc0, w0.w, hq.w);
          pkfma(lc1, w1.x, hq.x); pkfma(lc1, w1.y, hq.y);
          pkfma(lc1, w1.z, hq.z); pkfma(lc1, w1.w, hq.w);
        }
        l0 = allred8(cvt2f(lc0));
        l1 = allred8(cvt2f(lc1));
      }

      a0 = allred8(a0); a1 = allred8(a1); a2 = allred8(a2); a3 = allred8(a3);

      const float t0 = __uint_as_float(hbp[cur][160]);
      const float t1 = __uint_as_float(hbp[cur][161]);

      // update right rows: lane ks==0 owns 4 rows
      if (ks == 0) {
        float4 cv = *(const float4*)&cbuf[s][4 * g];
        float pre0 = a0 + wt[0].x * t0 + wt[0].y * t1 + cv.x;
        float pre1 = a1 + wt[1].x * t0 + wt[1].y * t1 + cv.y;
        float pre2 = a2 + wt[2].x * t0 + wt[2].y * t1 + cv.z;
        float pre3 = a3 + wt[3].x * t0 + wt[3].y * t1 + cv.w;
        hcur[0] = 0.8f * hcur[0] + 0.2f * my_tanh(pre0);
        hcur[1] = 0.8f * hcur[1] + 0.2f * my_tanh(pre1);
        hcur[2] = 0.8f * hcur[2] + 0.2f * my_tanh(pre2);
        hcur[3] = 0.8f * hcur[3] + 0.2f * my_tanh(pre3);
        uint32_t p01 = packh2(hcur[0], hcur[1]);
        uint32_t p23 = packh2(hcur[2], hcur[3]);
        if (g == 63) {               // rows 254,255 packed; 256,257 f32 tail
          hbp[nxt][PK(127)] = p01;
          hbp[nxt][160] = __float_as_uint(hcur[2]);
          hbp[nxt][161] = __float_as_uint(hcur[3]);
        } else {
          hbp[nxt][PK(1 + 2 * g)] = p01;
          hbp[nxt][PK(2 + 2 * g)] = p23;
        }
        *(float4*)&sbuf[s][4 * g] = make_float4(hcur[0], hcur[1], hcur[2], hcur[3]);
      }

      // left updater: lane 0 owns rows 0,1 (h[0],h[1] -> pair kp=0)
      if (tid == 0) {
        float wl0t0 = __uint_as_float(wlp[0][160]);
        float wl0t1 = __uint_as_float(wlp[0][161]);
        float wl1t0 = __uint_as_float(wlp[1][160]);
        float wl1t1 = __uint_as_float(wlp[1][161]);
        float pre0 = l0 + wl0t0 * t0 + wl0t1 * t1 + cbuf[s][256];
        float pre1 = l1 + wl1t0 * t0 + wl1t1 * t1 + cbuf[s][257];
        hL0 = 0.8f * hL0 + 0.2f * my_tanh(pre0);
        hL1 = 0.8f * hL1 + 0.2f * my_tanh(pre1);
        hbp[nxt][0] = packh2(hL0, hL1);   // PK(0) == 0
        sbuf[s][256] = hL0;
        sbuf[s][257] = hL1;
      }

      step_barrier();
    }

    // flush sbuf -> hs (coalesced)
    const int fb = cc * 2064;
    for (int idx = tid; idx < 2064; idx += 512) {
      int s = idx / 258, j = idx - 258 * s;
      int jj = (j < 2) ? (256 + j) : (j - 2);
      gO[fb + idx] = sbuf[s][jj];
    }

    // zs for the chunk's 8 timesteps: wave w handles s=w
    {
      int w = tid >> 6, lane = tid & 63;
      float zacc = 0.f;
#pragma unroll
      for (int q = 0; q < 5; ++q) {
        int jj = lane + 64 * q;
        if (jj < 258) zacc = fmaf(sbuf[w][jj], wrol[jj], zacc);
      }
#pragma unroll
      for (int m = 32; m >= 1; m >>= 1) zacc += __shfl_xor(zacc, m);
      if (lane == 0) gZ[cc * 8 + w] = zacc + bro;
    }

    // commit prefetched C chunk -> cbuf (compiler inserts the vmcnt wait for
    // the creg register dependency here — once per chunk, not per step)
    if (hn) {
#pragma unroll
      for (int q = 0; q < 5; ++q) {
        int idx = tid + 512 * q;
        if (idx < 2064) {
          int s = idx / 258, j = idx - 258 * s;
          int jj = (j < 2) ? (256 + j) : (j - 2);
          cbuf[s][jj] = creg[q];
        }
      }
    }
    step_barrier();
  }
}

// ---------------------------------------------------------------------------
extern "C" void kernel_launch(void* const* d_in, const int* in_sizes, int n_in,
                              void* d_out, int out_size, void* d_ws, size_t ws_size,
                              hipStream_t stream) {
  const float* xs   = (const float*)d_in[0];
  const float* w_ll = (const float*)d_in[1];
  const float* b_ll = (const float*)d_in[2];
  const float* w_rr = (const float*)d_in[3];
  const float* b_rr = (const float*)d_in[4];
  const float* w_lr = (const float*)d_in[5];
  const float* w_rl = (const float*)d_in[6];
  const float* w_xl = (const float*)d_in[7];
  const float* w_xr = (const float*)d_in[8];
  const float* w_ro = (const float*)d_in[9];
  const float* b_ro = (const float*)d_in[10];

  float* hs = (float*)d_out;                    // 512*400*258

  uint32_t* Wp  = (uint32_t*)d_ws;              // 258*128 = 33,024 u32
  float* Wtail  = (float*)(Wp + 33024);         // 516
  float* u      = Wtail + 516;                  // 409,600
  float* v      = u + 409600;                   // 409,600

  uint32_t nk[3][2];
  for (uint32_t i = 0; i < 3; ++i) {
    uint32_t o0, o1;
    tf2x32(0u, 42u, 0u, i, o0, o1);
    nk[i][0] = o0; nk[i][1] = o1;
  }

  build_w_kernel<<<129, 256, 0, stream>>>(w_ll, w_rl, w_lr, w_rr, Wp, Wtail);
  gen_uv_kernel<<<3200, 256, 0, stream>>>(xs, u, v, nk[0][0], nk[0][1], nk[1][0], nk[1][1]);
  gen_c_kernel<<<206400, 256, 0, stream>>>(u, v, w_xl, w_xr, b_ll, b_rr, hs, nk[2][0], nk[2][1]);
  rnn_scan_kernel<<<512, 512, 0, stream>>>(Wp, Wtail, hs, w_ro, b_ro);
}